// Round 1
// baseline (84.180 us; speedup 1.0000x reference)
//
#include <hip/hip_runtime.h>

// Problem shape (fixed by reference): A is 16384 x 512 fp32, output is 1 fp32 scalar.
//   s = column sums of A  (len 512)
//   out = (dot(s,s) - sum(A*A)) / (n*(n-1)),  n = 16384
#define NROWS  16384
#define NCOLS  512
#define NC4    128              // float4 column-groups per row
#define BLOCKS 256
#define TPB    1024
#define SLOTS  (TPB / NC4)      // 8 rows processed per block-iteration

__global__ __launch_bounds__(TPB) void ddc2_pass1(
    const float* __restrict__ A,
    float* __restrict__ colsum,   // [BLOCKS * NCOLS] per-block column partials
    float* __restrict__ sqsum)    // [BLOCKS] per-block sum(A*A) partials
{
    const int tid  = threadIdx.x;
    const int c4   = tid & (NC4 - 1);   // which float4 column group this thread owns
    const int slot = tid >> 7;          // 0..7 : row parity within the block
    const float4* __restrict__ A4 = (const float4*)A;

    float4 s = make_float4(0.f, 0.f, 0.f, 0.f);
    float  sq = 0.f;
    // Coalesced: consecutive lanes -> consecutive float4 columns of one row.
    for (int r = blockIdx.x * SLOTS + slot; r < NROWS; r += gridDim.x * SLOTS) {
        float4 v = A4[r * NC4 + c4];
        s.x += v.x; s.y += v.y; s.z += v.z; s.w += v.w;
        sq  += v.x * v.x + v.y * v.y + v.z * v.z + v.w * v.w;
    }

    // Reduce the 8 row-slots down to one float4 per column group (LDS tree).
    __shared__ float4 lds[TPB];   // 16 KiB
    lds[tid] = s;
    __syncthreads();
    for (int stride = TPB / 2; stride >= NC4; stride >>= 1) {
        if (tid < stride) {
            float4 o = lds[tid + stride];
            float4 m = lds[tid];
            m.x += o.x; m.y += o.y; m.z += o.z; m.w += o.w;
            lds[tid] = m;
        }
        __syncthreads();
    }
    if (tid < NC4) {
        ((float4*)colsum)[blockIdx.x * NC4 + tid] = lds[tid];
    }

    // Block reduction of sq: wave shuffle (width 64) then tiny LDS pass.
    for (int off = 32; off; off >>= 1) sq += __shfl_down(sq, off, 64);
    __shared__ float wsum[TPB / 64];
    if ((tid & 63) == 0) wsum[tid >> 6] = sq;
    __syncthreads();
    if (tid == 0) {
        float t = 0.f;
        for (int i = 0; i < TPB / 64; ++i) t += wsum[i];
        sqsum[blockIdx.x] = t;
    }
}

__global__ __launch_bounds__(128) void ddc2_pass2(
    const float* __restrict__ colsum,
    const float* __restrict__ sqsum,
    float* __restrict__ out)
{
    const int tid = threadIdx.x;  // 0..127, one float4 column group each
    const float4* __restrict__ cs4 = (const float4*)colsum;

    float4 acc = make_float4(0.f, 0.f, 0.f, 0.f);
    for (int b = 0; b < BLOCKS; ++b) {          // coalesced: lane-contiguous per b
        float4 v = cs4[b * NC4 + tid];
        acc.x += v.x; acc.y += v.y; acc.z += v.z; acc.w += v.w;
    }
    float total = acc.x * acc.x + acc.y * acc.y + acc.z * acc.z + acc.w * acc.w;
    float sq = sqsum[tid] + sqsum[tid + 128];

    for (int off = 32; off; off >>= 1) {
        total += __shfl_down(total, off, 64);
        sq    += __shfl_down(sq,    off, 64);
    }
    __shared__ float t2[2], q2[2];
    if ((tid & 63) == 0) { t2[tid >> 6] = total; q2[tid >> 6] = sq; }
    __syncthreads();
    if (tid == 0) {
        double T = (double)(t2[0] + t2[1]);
        double Q = (double)(q2[0] + q2[1]);
        const double denom = (double)NROWS * (double)(NROWS - 1);
        out[0] = (float)((T - Q) / denom);
    }
}

extern "C" void kernel_launch(void* const* d_in, const int* in_sizes, int n_in,
                              void* d_out, int out_size, void* d_ws, size_t ws_size,
                              hipStream_t stream) {
    const float* A = (const float*)d_in[0];
    float* out = (float*)d_out;

    // Workspace layout: [BLOCKS*NCOLS] column partials, then [BLOCKS] sq partials.
    float* colsum = (float*)d_ws;
    float* sqsum  = colsum + BLOCKS * NCOLS;   // 256*512*4 = 512 KiB offset

    ddc2_pass1<<<BLOCKS, TPB, 0, stream>>>(A, colsum, sqsum);
    ddc2_pass2<<<1, 128, 0, stream>>>(colsum, sqsum, out);
}

// Round 2
// 83.279 us; speedup vs baseline: 1.0108x; 1.0108x over previous
//
#include <hip/hip_runtime.h>

// A is 16384 x 512 fp32 -> scalar: (||colsum||^2 - sum(A*A)) / (n*(n-1))
#define NROWS  16384
#define NCOLS  512
#define NC4    128              // float4 column-groups per row
#define BLOCKS 256
#define TPB    1024
#define SLOTS  (TPB / NC4)      // 8 rows per block-iteration
#define ITERS  (NROWS / (BLOCKS * SLOTS))   // = 8, exact (16384/2048)

__global__ __launch_bounds__(TPB) void ddc2_pass1(
    const float* __restrict__ A,
    float* __restrict__ colsum,   // [BLOCKS * NCOLS] per-block column partials
    float* __restrict__ sqsum)    // [BLOCKS] per-block sum(A*A) partials
{
    const int tid  = threadIdx.x;
    const int c4   = tid & (NC4 - 1);   // float4 column group owned by this thread
    const int slot = tid >> 7;          // 0..7
    const float4* __restrict__ A4 = (const float4*)A;

    // base row < 2048; r = base + k*2048 < 16384 for k in [0,8) — no bounds checks.
    const int base = blockIdx.x * SLOTS + slot;

    float4 s = make_float4(0.f, 0.f, 0.f, 0.f);
    float  sq = 0.f;
#pragma unroll
    for (int k = 0; k < ITERS; ++k) {
        float4 v = A4[(base + k * (BLOCKS * SLOTS)) * NC4 + c4];
        s.x += v.x; s.y += v.y; s.z += v.z; s.w += v.w;
        sq  += v.x * v.x + v.y * v.y + v.z * v.z + v.w * v.w;
    }

    // Fold 8 row-slots into one float4 per column group.
    __shared__ float4 lds[TPB];   // 16 KiB
    lds[tid] = s;
    __syncthreads();
#pragma unroll
    for (int stride = TPB / 2; stride >= NC4; stride >>= 1) {
        if (tid < stride) {
            float4 o = lds[tid + stride];
            float4 m = lds[tid];
            m.x += o.x; m.y += o.y; m.z += o.z; m.w += o.w;
            lds[tid] = m;
        }
        __syncthreads();
    }
    if (tid < NC4) {
        ((float4*)colsum)[blockIdx.x * NC4 + tid] = lds[tid];
    }

    // Block-reduce sq: wave shuffle then tiny LDS pass.
#pragma unroll
    for (int off = 32; off; off >>= 1) sq += __shfl_down(sq, off, 64);
    __shared__ float wsum[TPB / 64];
    if ((tid & 63) == 0) wsum[tid >> 6] = sq;
    __syncthreads();
    if (tid == 0) {
        float t = 0.f;
#pragma unroll
        for (int i = 0; i < TPB / 64; ++i) t += wsum[i];
        sqsum[blockIdx.x] = t;
    }
}

__global__ __launch_bounds__(512) void ddc2_pass2(
    const float* __restrict__ colsum,
    const float* __restrict__ sqsum,
    float* __restrict__ out)
{
    const int tid = threadIdx.x;        // 0..511, one column each

    float acc = 0.f;
#pragma unroll 8
    for (int b = 0; b < BLOCKS; ++b) {  // coalesced: lanes contiguous per b
        acc += colsum[b * NCOLS + tid];
    }
    float total = acc * acc;
    float sq = (tid < BLOCKS) ? sqsum[tid] : 0.f;

#pragma unroll
    for (int off = 32; off; off >>= 1) {
        total += __shfl_down(total, off, 64);
        sq    += __shfl_down(sq,    off, 64);
    }
    __shared__ float t8[8], q8[8];
    if ((tid & 63) == 0) { t8[tid >> 6] = total; q8[tid >> 6] = sq; }
    __syncthreads();
    if (tid == 0) {
        double T = 0.0, Q = 0.0;
#pragma unroll
        for (int i = 0; i < 8; ++i) { T += t8[i]; Q += q8[i]; }
        const double denom = (double)NROWS * (double)(NROWS - 1);
        out[0] = (float)((T - Q) / denom);
    }
}

extern "C" void kernel_launch(void* const* d_in, const int* in_sizes, int n_in,
                              void* d_out, int out_size, void* d_ws, size_t ws_size,
                              hipStream_t stream) {
    const float* A = (const float*)d_in[0];
    float* out = (float*)d_out;

    float* colsum = (float*)d_ws;
    float* sqsum  = colsum + BLOCKS * NCOLS;   // 512 KiB offset

    ddc2_pass1<<<BLOCKS, TPB, 0, stream>>>(A, colsum, sqsum);
    ddc2_pass2<<<1, 512, 0, stream>>>(colsum, sqsum, out);
}

// Round 3
// 81.757 us; speedup vs baseline: 1.0296x; 1.0186x over previous
//
#include <hip/hip_runtime.h>

// A is 16384 x 512 fp32 -> scalar: (||colsum||^2 - sum(A*A)) / (n*(n-1))
// Single fused kernel: per-block column partials -> device-scope fp32 atomics
// into a 512-float accumulator; last block (counter pattern) finalizes.
#define NROWS  16384
#define NCOLS  512
#define NC4    128              // float4 column-groups per row
#define BLOCKS 256
#define TPB    1024
#define SLOTS  (TPB / NC4)      // 8 rows per block-iteration
#define ITERS  (NROWS / (BLOCKS * SLOTS))   // = 8, exact

__global__ __launch_bounds__(TPB) void ddc2_fused(
    const float* __restrict__ A,
    float* __restrict__ colsum,          // [512], zero-initialized by memset node
    float* __restrict__ sqsum,           // [1],   zero-initialized
    unsigned int* __restrict__ counter,  // [1],   zero-initialized
    float* __restrict__ out)
{
    const int tid  = threadIdx.x;
    const int c4   = tid & (NC4 - 1);   // float4 column group owned by this thread
    const int slot = tid >> 7;          // 0..7
    const float4* __restrict__ A4 = (const float4*)A;
    const int base = blockIdx.x * SLOTS + slot;   // < 2048; +k*2048 stays < 16384

    float4 s = make_float4(0.f, 0.f, 0.f, 0.f);
    float  sq = 0.f;
#pragma unroll
    for (int k = 0; k < ITERS; ++k) {   // 8 independent 1KB/wave coalesced loads
        float4 v = A4[(base + k * (BLOCKS * SLOTS)) * NC4 + c4];
        s.x += v.x; s.y += v.y; s.z += v.z; s.w += v.w;
        sq  += v.x * v.x + v.y * v.y + v.z * v.z + v.w * v.w;
    }

    // Fold 8 row-slots into one float4 per column group.
    __shared__ float4 lds[TPB];   // 16 KiB
    lds[tid] = s;
    __syncthreads();
#pragma unroll
    for (int stride = TPB / 2; stride >= NC4; stride >>= 1) {
        if (tid < stride) {
            float4 o = lds[tid + stride];
            float4 m = lds[tid];
            m.x += o.x; m.y += o.y; m.z += o.z; m.w += o.w;
            lds[tid] = m;
        }
        __syncthreads();
    }

    // Block-reduce sq: wave shuffle then tiny LDS pass.
#pragma unroll
    for (int off = 32; off; off >>= 1) sq += __shfl_down(sq, off, 64);
    __shared__ float wsum[TPB / 64];
    if ((tid & 63) == 0) wsum[tid >> 6] = sq;
    __syncthreads();

    // Device-scope accumulation: 512 scalar fp32 atomics (8 waves, coalesced
    // consecutive addresses) + one sq atomic.
    if (tid < NCOLS) {
        atomicAdd(&colsum[tid], ((const float*)lds)[tid]);
    }
    if (tid == 0) {
        float t = 0.f;
#pragma unroll
        for (int i = 0; i < TPB / 64; ++i) t += wsum[i];
        atomicAdd(sqsum, t);
    }

    // Barrier implies s_waitcnt vmcnt(0): this block's atomics are complete at
    // the device coherence point before tid 0 bumps the counter.
    __syncthreads();
    __shared__ int is_last;
    if (tid == 0) {
        unsigned int prev = __hip_atomic_fetch_add(counter, 1u,
                              __ATOMIC_ACQ_REL, __HIP_MEMORY_SCOPE_AGENT);
        is_last = (prev == BLOCKS - 1);
    }
    __syncthreads();
    if (!is_last) return;   // block-uniform

    // Last block: read back final column sums with agent-scope loads
    // (per-XCD L2 is not coherent for plain loads), square, reduce.
    float total = 0.f;
    if (tid < NCOLS) {
        float v = __hip_atomic_load(&colsum[tid], __ATOMIC_RELAXED,
                                    __HIP_MEMORY_SCOPE_AGENT);
        total = v * v;
    }
#pragma unroll
    for (int off = 32; off; off >>= 1) total += __shfl_down(total, off, 64);
    __syncthreads();                     // wsum reuse: sq readers are done
    if ((tid & 63) == 0) wsum[tid >> 6] = total;
    __syncthreads();
    if (tid == 0) {
        double T = 0.0;
#pragma unroll
        for (int i = 0; i < TPB / 64; ++i) T += wsum[i];
        double Q = (double)__hip_atomic_load(sqsum, __ATOMIC_RELAXED,
                                             __HIP_MEMORY_SCOPE_AGENT);
        const double denom = (double)NROWS * (double)(NROWS - 1);
        out[0] = (float)((T - Q) / denom);
    }
}

extern "C" void kernel_launch(void* const* d_in, const int* in_sizes, int n_in,
                              void* d_out, int out_size, void* d_ws, size_t ws_size,
                              hipStream_t stream) {
    const float* A = (const float*)d_in[0];
    float* out = (float*)d_out;

    // ws layout: colsum[512] @0, sqsum @2048, counter @2052  (2056 bytes)
    float* colsum = (float*)d_ws;
    float* sqsum  = (float*)((char*)d_ws + 2048);
    unsigned int* counter = (unsigned int*)((char*)d_ws + 2052);

    hipMemsetAsync(d_ws, 0, 2056, stream);   // zero accumulators (graph memset node)
    ddc2_fused<<<BLOCKS, TPB, 0, stream>>>(A, colsum, sqsum, counter, out);
}